// Round 3
// baseline (1649.392 us; speedup 1.0000x reference)
//
#include <hip/hip_runtime.h>
#include <math.h>

#define N_NODES 30000
#define D_IN    256
#define E_EDGES 300000
#define T_TYPES 2
#define HEADS   8
#define HID     64
#define F1      512   // HEADS*HID
#define OUT_F   256
#define EP      (E_EDGES + N_NODES)   // 330000 edges per type incl self-loops

// ---------------------------------------------------------------------------
// utility: zero an int buffer
// ---------------------------------------------------------------------------
__global__ void zero_kernel(int* __restrict__ p, int n) {
    int i = blockIdx.x * blockDim.x + threadIdx.x;
    if (i < n) p[i] = 0;
}

// ---------------------------------------------------------------------------
// CSR build: histogram -> scan -> scatter. Graph identical for both convs.
// ---------------------------------------------------------------------------
__global__ void hist_kernel(const int* __restrict__ ei, int* __restrict__ count) {
    int idx = blockIdx.x * blockDim.x + threadIdx.x;
    if (idx >= T_TYPES * EP) return;
    int t = idx / EP, i = idx - t * EP;
    int dst = (i < E_EDGES) ? ei[t * 2 * E_EDGES + E_EDGES + i] : (i - E_EDGES);
    atomicAdd(&count[t * N_NODES + dst], 1);
}

#define SCAN_T  1024
#define SCAN_CH 30   // 1024*30 = 30720 >= 30000

__global__ __launch_bounds__(SCAN_T) void scan_kernel(int* __restrict__ count,
                                                      int* __restrict__ offsets) {
    __shared__ int sums[SCAN_T];
    int tid = threadIdx.x;
    for (int t = 0; t < T_TYPES; ++t) {
        int* cnt = count + t * N_NODES;
        int* off = offsets + t * (N_NODES + 1);
        int c0 = tid * SCAN_CH;
        int local[SCAN_CH];
        int sum = 0;
        #pragma unroll
        for (int i = 0; i < SCAN_CH; ++i) {
            int d = c0 + i;
            int v = (d < N_NODES) ? cnt[d] : 0;
            local[i] = sum;   // exclusive within chunk
            sum += v;
        }
        sums[tid] = sum;
        __syncthreads();
        for (int ofs = 1; ofs < SCAN_T; ofs <<= 1) {
            int v = 0;
            if (tid >= ofs) v = sums[tid - ofs];
            __syncthreads();
            sums[tid] += v;
            __syncthreads();
        }
        int base = sums[tid] - sum;   // exclusive prefix of this chunk
        #pragma unroll
        for (int i = 0; i < SCAN_CH; ++i) {
            int d = c0 + i;
            if (d < N_NODES) { off[d] = base + local[i]; cnt[d] = 0; }  // cnt reused as cursor
        }
        if (tid == SCAN_T - 1) off[N_NODES] = sums[SCAN_T - 1];
        __syncthreads();
    }
}

__global__ void scatter_kernel(const int* __restrict__ ei, const int* __restrict__ offsets,
                               int* __restrict__ cursor, int* __restrict__ csr_src) {
    int idx = blockIdx.x * blockDim.x + threadIdx.x;
    if (idx >= T_TYPES * EP) return;
    int t = idx / EP, i = idx - t * EP;
    int src, dst;
    if (i < E_EDGES) {
        src = ei[t * 2 * E_EDGES + i];
        dst = ei[t * 2 * E_EDGES + E_EDGES + i];
    } else {
        src = dst = i - E_EDGES;
    }
    int pos = offsets[t * (N_NODES + 1) + dst] + atomicAdd(&cursor[t * N_NODES + dst], 1);
    csr_src[t * EP + pos] = src;
}

// ---------------------------------------------------------------------------
// fp32 GEMM with strides: C[M x Nc] = A[M x K] @ W[K x Nc] + bias[Nc]
// A row stride lda, W row stride ldw, C row stride ldc. Nc%64==0, K%16==0.
// 64x64 tile, 256 threads, 4x4 per thread.
// ---------------------------------------------------------------------------
__global__ __launch_bounds__(256) void gemm_bias_kernel(
        const float* __restrict__ A, int lda,
        const float* __restrict__ W, int ldw,
        const float* __restrict__ bias,
        float* __restrict__ C, int ldc,
        int M, int K, int Nc) {
    __shared__ float As[16][64];  // [k][m]
    __shared__ float Bs[16][64];  // [k][n]
    int tid = threadIdx.x;
    int tx = tid & 15, ty = tid >> 4;
    int row0 = blockIdx.y * 64, col0 = blockIdx.x * 64;
    int ar = tid >> 2, akk = (tid & 3) * 4;   // A staging: row, k-quad
    int bkk = tid >> 4, bc = (tid & 15) * 4;  // B staging: k, col-quad
    float acc[4][4] = {};
    for (int k0 = 0; k0 < K; k0 += 16) {
        float4 av = make_float4(0.f, 0.f, 0.f, 0.f);
        if (row0 + ar < M)
            av = *(const float4*)&A[(size_t)(row0 + ar) * lda + k0 + akk];
        As[akk + 0][ar] = av.x; As[akk + 1][ar] = av.y;
        As[akk + 2][ar] = av.z; As[akk + 3][ar] = av.w;
        float4 bv = *(const float4*)&W[(size_t)(k0 + bkk) * ldw + col0 + bc];
        *(float4*)&Bs[bkk][bc] = bv;
        __syncthreads();
        #pragma unroll
        for (int kk = 0; kk < 16; ++kk) {
            float a_[4], b_[4];
            #pragma unroll
            for (int i = 0; i < 4; ++i) a_[i] = As[kk][ty * 4 + i];
            #pragma unroll
            for (int j = 0; j < 4; ++j) b_[j] = Bs[kk][tx * 4 + j];
            #pragma unroll
            for (int i = 0; i < 4; ++i)
                #pragma unroll
                for (int j = 0; j < 4; ++j)
                    acc[i][j] += a_[i] * b_[j];
        }
        __syncthreads();
    }
    #pragma unroll
    for (int i = 0; i < 4; ++i) {
        int r = row0 + ty * 4 + i;
        if (r >= M) continue;
        #pragma unroll
        for (int j = 0; j < 4; ++j) {
            int c = col0 + tx * 4 + j;
            C[(size_t)r * ldc + c] = acc[i][j] + bias[c];
        }
    }
}

// ---------------------------------------------------------------------------
// Fused GATv2 edge kernel over a 256-column block. One wave per destination.
// Lane owns 4 channels (q4 = lane*4). RW = lanes per head (16 for 4-head
// blocks of conv1, 64 for conv2's single head). Online softmax, zero atomics.
// xl/xr are compact [N][256]; out has row stride ldo with column offset
// already folded into the pointer.
// ---------------------------------------------------------------------------
template <int RW>
__global__ __launch_bounds__(256) void gat_edge_kernel(
        const float* __restrict__ xl, const float* __restrict__ xr,
        const float* __restrict__ att,          // [256] slice
        const int* __restrict__ offs,           // [N+1]
        const int* __restrict__ csr,            // [EP]
        float* __restrict__ out, int ldo, int add_mode) {
    int wave = (blockIdx.x * blockDim.x + threadIdx.x) >> 6;
    int lane = threadIdx.x & 63;
    if (wave >= N_NODES) return;
    int d = wave;
    int q4 = lane * 4;
    float attr[4], xrr[4];
    *(float4*)&attr[0] = *(const float4*)&att[q4];
    *(float4*)&xrr[0]  = *(const float4*)&xr[(size_t)d * 256 + q4];
    float m = -INFINITY, s = 0.f;
    float acc[4] = {0.f, 0.f, 0.f, 0.f};
    int p0 = offs[d], p1 = offs[d + 1];
    for (int p = p0; p < p1; ++p) {
        int srcn = csr[p];
        float xv[4];
        *(float4*)&xv[0] = *(const float4*)&xl[(size_t)srcn * 256 + q4];
        float e = 0.f;
        #pragma unroll
        for (int q = 0; q < 4; ++q) {
            float h = xv[q] + xrr[q];
            h = (h > 0.f) ? h : 0.2f * h;       // leaky_relu(., 0.2)
            e += attr[q] * h;
        }
        #pragma unroll
        for (int msk = 1; msk < RW; msk <<= 1) e += __shfl_xor(e, msk);
        float mn = fmaxf(m, e);
        float sc = __expf(m - mn);              // m==-inf -> 0
        float pe = __expf(e - mn);
        s = s * sc + pe;
        #pragma unroll
        for (int q = 0; q < 4; ++q) acc[q] = acc[q] * sc + pe * xv[q];
        m = mn;
    }
    float inv = 1.f / s;
    float* dp = &out[(size_t)d * ldo + q4];
    if (add_mode) {
        #pragma unroll
        for (int q = 0; q < 4; ++q) dp[q] += acc[q] * inv;
    } else {
        *(float4*)dp = make_float4(acc[0] * inv, acc[1] * inv, acc[2] * inv, acc[3] * inv);
    }
}

// ---------------------------------------------------------------------------
// h = elu(h + b0[c] + b1[c])   (per-type biases summed; zeros in setup but correct)
// ---------------------------------------------------------------------------
__global__ void elu_bias_kernel(float* __restrict__ h, const float* __restrict__ b0,
                                const float* __restrict__ b1, int total, int F) {
    int idx = blockIdx.x * blockDim.x + threadIdx.x;
    if (idx >= total) return;
    int c = idx % F;
    float v = h[idx] + b0[c] + b1[c];
    h[idx] = (v > 0.f) ? v : (__expf(v) - 1.f);
}

// ---------------------------------------------------------------------------
extern "C" void kernel_launch(void* const* d_in, const int* in_sizes, int n_in,
                              void* d_out, int out_size, void* d_ws, size_t ws_size,
                              hipStream_t stream) {
    const float* x      = (const float*)d_in[0];
    const int*   ei     = (const int*)d_in[1];
    const float* w1_l   = (const float*)d_in[2];
    const float* b1_l   = (const float*)d_in[3];
    const float* w1_r   = (const float*)d_in[4];
    const float* b1_r   = (const float*)d_in[5];
    const float* att1   = (const float*)d_in[6];
    const float* bias1  = (const float*)d_in[7];
    const float* w2_l   = (const float*)d_in[8];
    const float* b2_l   = (const float*)d_in[9];
    const float* w2_r   = (const float*)d_in[10];
    const float* b2_r   = (const float*)d_in[11];
    const float* att2   = (const float*)d_in[12];
    const float* bias2  = (const float*)d_in[13];
    const float* w_lin  = (const float*)d_in[14];
    const float* b_lin  = (const float*)d_in[15];
    float* out = (float*)d_out;

    // ---- workspace layout (~126 MB) ----
    float* h1   = (float*)d_ws;                        // [N][512]  61.4 MB
    float* bufA = h1 + (size_t)N_NODES * F1;           // [N][256]  30.7 MB
    float* bufB = bufA + (size_t)N_NODES * OUT_F;      // [N][256]  30.7 MB
    int* count   = (int*)(bufB + (size_t)N_NODES * OUT_F);
    int* offsets = count + T_TYPES * N_NODES;
    int* csr     = offsets + T_TYPES * (N_NODES + 1);  // [T][EP]   2.64 MB
    float* h2 = out;                                   // conv2 output lives in d_out

    // --- build CSR (by dst), shared by both convs ---
    zero_kernel<<<(T_TYPES * N_NODES + 255) / 256, 256, 0, stream>>>(count, T_TYPES * N_NODES);
    int eblocks = (T_TYPES * EP + 255) / 256;
    hist_kernel<<<eblocks, 256, 0, stream>>>(ei, count);
    scan_kernel<<<1, SCAN_T, 0, stream>>>(count, offsets);
    scatter_kernel<<<eblocks, 256, 0, stream>>>(ei, offsets, count, csr);

    int gat_blocks = N_NODES / 4;                 // 4 waves/block, one wave per dst
    dim3 gq(OUT_F / 64, (N_NODES + 63) / 64);     // 256-col GEMM grid

    // --- conv1: per type t and head-half, xl/xr GEMMs then fused edge kernel ---
    for (int t = 0; t < T_TYPES; ++t) {
        for (int hh = 0; hh < 2; ++hh) {
            int co = hh * 256;   // column offset into the 512-wide conv1 space
            gemm_bias_kernel<<<gq, 256, 0, stream>>>(
                x, D_IN, w1_l + (size_t)t * D_IN * F1 + co, F1,
                b1_l + t * F1 + co, bufA, OUT_F, N_NODES, D_IN, OUT_F);
            gemm_bias_kernel<<<gq, 256, 0, stream>>>(
                x, D_IN, w1_r + (size_t)t * D_IN * F1 + co, F1,
                b1_r + t * F1 + co, bufB, OUT_F, N_NODES, D_IN, OUT_F);
            gat_edge_kernel<16><<<gat_blocks, 256, 0, stream>>>(
                bufA, bufB, att1 + t * F1 + co, offsets + t * (N_NODES + 1),
                csr + (size_t)t * EP, h1 + co, F1, t);
        }
    }
    elu_bias_kernel<<<(N_NODES * F1 + 255) / 256, 256, 0, stream>>>(
        h1, bias1, bias1 + F1, N_NODES * F1, F1);

    // --- conv2 (1 head, 256 cols) ---
    for (int t = 0; t < T_TYPES; ++t) {
        gemm_bias_kernel<<<gq, 256, 0, stream>>>(
            h1, F1, w2_l + (size_t)t * F1 * OUT_F, OUT_F,
            b2_l + t * OUT_F, bufA, OUT_F, N_NODES, F1, OUT_F);
        gemm_bias_kernel<<<gq, 256, 0, stream>>>(
            h1, F1, w2_r + (size_t)t * F1 * OUT_F, OUT_F,
            b2_r + t * OUT_F, bufB, OUT_F, N_NODES, F1, OUT_F);
        gat_edge_kernel<64><<<gat_blocks, 256, 0, stream>>>(
            bufA, bufB, att2 + t * OUT_F, offsets + t * (N_NODES + 1),
            csr + (size_t)t * EP, h2, OUT_F, t);
    }
    elu_bias_kernel<<<(N_NODES * OUT_F + 255) / 256, 256, 0, stream>>>(
        h2, bias2, bias2 + OUT_F, N_NODES * OUT_F, OUT_F);

    // --- final linear: copy h2 (in d_out) to bufA, then GEMM back into d_out ---
    hipMemcpyAsync(bufA, h2, (size_t)N_NODES * OUT_F * sizeof(float),
                   hipMemcpyDeviceToDevice, stream);
    gemm_bias_kernel<<<gq, 256, 0, stream>>>(
        bufA, OUT_F, w_lin, OUT_F, b_lin, out, OUT_F, N_NODES, OUT_F, OUT_F);
}

// Round 4
// 1090.489 us; speedup vs baseline: 1.5125x; 1.5125x over previous
//
#include <hip/hip_runtime.h>
#include <math.h>

#define N_NODES 30000
#define D_IN    256
#define E_EDGES 300000
#define T_TYPES 2
#define HEADS   8
#define HID     64
#define F1      512   // HEADS*HID
#define OUT_F   256
#define EP      (E_EDGES + N_NODES)   // 330000 edges per type incl self-loops

typedef __attribute__((ext_vector_type(8))) short bf16x8;
typedef __attribute__((ext_vector_type(4))) float f32x4;

__device__ __forceinline__ unsigned short f2bf(float f) {
    unsigned u = __float_as_uint(f);
    unsigned r = 0x7fffu + ((u >> 16) & 1u);
    return (unsigned short)((u + r) >> 16);
}
__device__ __forceinline__ float bf2f(unsigned short h) {
    return __uint_as_float(((unsigned)h) << 16);
}

// ---------------------------------------------------------------------------
// utility: zero an int buffer
// ---------------------------------------------------------------------------
__global__ void zero_kernel(int* __restrict__ p, int n) {
    int i = blockIdx.x * blockDim.x + threadIdx.x;
    if (i < n) p[i] = 0;
}

// ---------------------------------------------------------------------------
// CSR build: histogram -> scan -> scatter. Graph identical for both convs.
// ---------------------------------------------------------------------------
__global__ void hist_kernel(const int* __restrict__ ei, int* __restrict__ count) {
    int idx = blockIdx.x * blockDim.x + threadIdx.x;
    if (idx >= T_TYPES * EP) return;
    int t = idx / EP, i = idx - t * EP;
    int dst = (i < E_EDGES) ? ei[t * 2 * E_EDGES + E_EDGES + i] : (i - E_EDGES);
    atomicAdd(&count[t * N_NODES + dst], 1);
}

#define SCAN_T  1024
#define SCAN_CH 30   // 1024*30 = 30720 >= 30000

__global__ __launch_bounds__(SCAN_T) void scan_kernel(int* __restrict__ count,
                                                      int* __restrict__ offsets) {
    __shared__ int sums[SCAN_T];
    int tid = threadIdx.x;
    for (int t = 0; t < T_TYPES; ++t) {
        int* cnt = count + t * N_NODES;
        int* off = offsets + t * (N_NODES + 1);
        int c0 = tid * SCAN_CH;
        int local[SCAN_CH];
        int sum = 0;
        #pragma unroll
        for (int i = 0; i < SCAN_CH; ++i) {
            int d = c0 + i;
            int v = (d < N_NODES) ? cnt[d] : 0;
            local[i] = sum;
            sum += v;
        }
        sums[tid] = sum;
        __syncthreads();
        for (int ofs = 1; ofs < SCAN_T; ofs <<= 1) {
            int v = 0;
            if (tid >= ofs) v = sums[tid - ofs];
            __syncthreads();
            sums[tid] += v;
            __syncthreads();
        }
        int base = sums[tid] - sum;
        #pragma unroll
        for (int i = 0; i < SCAN_CH; ++i) {
            int d = c0 + i;
            if (d < N_NODES) { off[d] = base + local[i]; cnt[d] = 0; }
        }
        if (tid == SCAN_T - 1) off[N_NODES] = sums[SCAN_T - 1];
        __syncthreads();
    }
}

__global__ void scatter_kernel(const int* __restrict__ ei, const int* __restrict__ offsets,
                               int* __restrict__ cursor, int* __restrict__ csr_src) {
    int idx = blockIdx.x * blockDim.x + threadIdx.x;
    if (idx >= T_TYPES * EP) return;
    int t = idx / EP, i = idx - t * EP;
    int src, dst;
    if (i < E_EDGES) {
        src = ei[t * 2 * E_EDGES + i];
        dst = ei[t * 2 * E_EDGES + E_EDGES + i];
    } else {
        src = dst = i - E_EDGES;
    }
    int pos = offsets[t * (N_NODES + 1) + dst] + atomicAdd(&cursor[t * N_NODES + dst], 1);
    csr_src[t * EP + pos] = src;
}

// ---------------------------------------------------------------------------
// Weight pre-transpose + bf16 hi/lo split. Output layout: Wt[n][k] (B^T).
// conv1: 8 mats [K=256][N=256], mat = ((t*2+lr)*2+h)
// ---------------------------------------------------------------------------
__global__ void wconv1_kernel(const float* __restrict__ w1_l, const float* __restrict__ w1_r,
                              unsigned short* __restrict__ dh, unsigned short* __restrict__ dl) {
    int idx = blockIdx.x * blockDim.x + threadIdx.x;   // 8*65536
    if (idx >= 8 * 65536) return;
    int n = idx & 255, k = (idx >> 8) & 255, mat = idx >> 16;
    int h = mat & 1, lr = (mat >> 1) & 1, t = mat >> 2;
    const float* src = lr ? w1_r : w1_l;
    float v = src[(size_t)t * 256 * 512 + (size_t)k * 512 + h * 256 + n];
    unsigned short hi = f2bf(v);
    unsigned short lo = f2bf(v - bf2f(hi));
    size_t o = (size_t)mat * 65536 + (size_t)n * 256 + k;
    dh[o] = hi; dl[o] = lo;
}

// conv2: 4 mats [K=512][N=256], mat = t*2+lr
__global__ void wconv2_kernel(const float* __restrict__ w2_l, const float* __restrict__ w2_r,
                              unsigned short* __restrict__ dh, unsigned short* __restrict__ dl) {
    int idx = blockIdx.x * blockDim.x + threadIdx.x;   // 4*131072
    if (idx >= 4 * 131072) return;
    int n = idx & 255, k = (idx >> 8) & 511, mat = idx >> 17;
    int lr = mat & 1, t = mat >> 1;
    const float* src = lr ? w2_r : w2_l;
    float v = src[(size_t)t * 512 * 256 + (size_t)k * 256 + n];
    unsigned short hi = f2bf(v);
    unsigned short lo = f2bf(v - bf2f(hi));
    size_t o = (size_t)mat * 131072 + (size_t)n * 512 + k;
    dh[o] = hi; dl[o] = lo;
}

// w_lin: [256][256]
__global__ void wlin_kernel(const float* __restrict__ w_lin,
                            unsigned short* __restrict__ dh, unsigned short* __restrict__ dl) {
    int idx = blockIdx.x * blockDim.x + threadIdx.x;   // 65536
    if (idx >= 65536) return;
    int n = idx & 255, k = idx >> 8;
    float v = w_lin[k * 256 + n];
    unsigned short hi = f2bf(v);
    unsigned short lo = f2bf(v - bf2f(hi));
    size_t o = (size_t)n * 256 + k;
    dh[o] = hi; dl[o] = lo;
}

// ---------------------------------------------------------------------------
// Split-precision bf16x3 MFMA GEMM: C[M x 256] = A[M x K](fp32) @ W + bias.
// W given as pre-split B^T: Wh/Wl [256][K] bf16. Tile BM=64 x BN=256 x BK=32,
// 256 threads (4 waves), wave w owns cols [w*64, w*64+64), 4x4 16x16 frags.
// A is fp32, split to hi/lo while staging; XOR granule swizzle on A-tile so
// both the b64 writes and b128 fragment reads are LDS-conflict-free.
// ---------------------------------------------------------------------------
__global__ __launch_bounds__(256) void gemm_mfma_kernel(
        const float* __restrict__ A, int lda,
        const unsigned short* __restrict__ Bh, const unsigned short* __restrict__ Bl,
        const float* __restrict__ bias,
        float* __restrict__ C, int M, int K) {
    __shared__ unsigned short Ah_s[64 * 32], Al_s[64 * 32];
    __shared__ unsigned short Bh_s[256 * 32], Bl_s[256 * 32];
    int t = threadIdx.x;
    int row0 = blockIdx.x * 64;
    int w = t >> 6;       // wave 0..3
    int l = t & 63;
    int fm = l & 15;      // fragment row/col
    int fg = l >> 4;      // fragment k-group

    f32x4 acc[4][4];
    const f32x4 zf = {0.f, 0.f, 0.f, 0.f};
    #pragma unroll
    for (int i = 0; i < 4; ++i)
        #pragma unroll
        for (int j = 0; j < 4; ++j) acc[i][j] = zf;

    int ar = t >> 3;      // A staging row 0..31 (+32v)
    int af = t & 7;       // A staging float4 idx in row
    int bn = t >> 2;      // B staging row 0..63 (+64g)
    int bb = t & 3;       // B staging 16B chunk

    for (int k0 = 0; k0 < K; k0 += 32) {
        // ---- stage A (fp32 -> bf16 hi/lo, swizzled) ----
        #pragma unroll
        for (int v = 0; v < 2; ++v) {
            int r = v * 32 + ar;
            int rg = row0 + r;
            float4 a4 = make_float4(0.f, 0.f, 0.f, 0.f);
            if (rg < M) a4 = *(const float4*)&A[(size_t)rg * lda + k0 + af * 4];
            ushort4 hi, lo;
            hi.x = f2bf(a4.x); lo.x = f2bf(a4.x - bf2f(hi.x));
            hi.y = f2bf(a4.y); lo.y = f2bf(a4.y - bf2f(hi.y));
            hi.z = f2bf(a4.z); lo.z = f2bf(a4.z - bf2f(hi.z));
            hi.w = f2bf(a4.w); lo.w = f2bf(a4.w - bf2f(hi.w));
            int ke = (af * 4) ^ (((r >> 1) & 3) << 3);
            *(ushort4*)&Ah_s[r * 32 + ke] = hi;
            *(ushort4*)&Al_s[r * 32 + ke] = lo;
        }
        // ---- stage B (already bf16 hi/lo in B^T layout, linear) ----
        #pragma unroll
        for (int g = 0; g < 4; ++g) {
            int n = g * 64 + bn;
            *(uint4*)&Bh_s[n * 32 + bb * 8] = *(const uint4*)&Bh[(size_t)n * K + k0 + bb * 8];
            *(uint4*)&Bl_s[n * 32 + bb * 8] = *(const uint4*)&Bl[(size_t)n * K + k0 + bb * 8];
        }
        __syncthreads();
        // ---- fragments ----
        bf16x8 ah[4], al[4], bh[4], bl[4];
        #pragma unroll
        for (int i = 0; i < 4; ++i) {
            int r = i * 16 + fm;
            int ke = (fg * 8) ^ (((r >> 1) & 3) << 3);
            ah[i] = *(const bf16x8*)&Ah_s[r * 32 + ke];
            al[i] = *(const bf16x8*)&Al_s[r * 32 + ke];
        }
        #pragma unroll
        for (int j = 0; j < 4; ++j) {
            int n = w * 64 + j * 16 + fm;
            bh[j] = *(const bf16x8*)&Bh_s[n * 32 + fg * 8];
            bl[j] = *(const bf16x8*)&Bl_s[n * 32 + fg * 8];
        }
        // ---- 48 MFMA: hh + hl + lh ----
        #pragma unroll
        for (int i = 0; i < 4; ++i)
            #pragma unroll
            for (int j = 0; j < 4; ++j) {
                acc[i][j] = __builtin_amdgcn_mfma_f32_16x16x32_bf16(ah[i], bh[j], acc[i][j], 0, 0, 0);
                acc[i][j] = __builtin_amdgcn_mfma_f32_16x16x32_bf16(ah[i], bl[j], acc[i][j], 0, 0, 0);
                acc[i][j] = __builtin_amdgcn_mfma_f32_16x16x32_bf16(al[i], bh[j], acc[i][j], 0, 0, 0);
            }
        __syncthreads();
    }
    // ---- epilogue: bias + store (C/D map: col=lane&15, row=(lane>>4)*4+q) ----
    #pragma unroll
    for (int j = 0; j < 4; ++j) {
        int col = w * 64 + j * 16 + fm;
        float bv = bias[col];
        #pragma unroll
        for (int i = 0; i < 4; ++i) {
            #pragma unroll
            for (int q = 0; q < 4; ++q) {
                int rg = row0 + i * 16 + fg * 4 + q;
                if (rg < M) C[(size_t)rg * 256 + col] = acc[i][j][q] + bv;
            }
        }
    }
}

// ---------------------------------------------------------------------------
// Fused GATv2 edge kernel over a 256-column block. One wave per destination.
// ---------------------------------------------------------------------------
template <int RW>
__global__ __launch_bounds__(256) void gat_edge_kernel(
        const float* __restrict__ xl, const float* __restrict__ xr,
        const float* __restrict__ att,
        const int* __restrict__ offs, const int* __restrict__ csr,
        float* __restrict__ out, int ldo, int add_mode) {
    int wave = (blockIdx.x * blockDim.x + threadIdx.x) >> 6;
    int lane = threadIdx.x & 63;
    if (wave >= N_NODES) return;
    int d = wave;
    int q4 = lane * 4;
    float attr[4], xrr[4];
    *(float4*)&attr[0] = *(const float4*)&att[q4];
    *(float4*)&xrr[0]  = *(const float4*)&xr[(size_t)d * 256 + q4];
    float m = -INFINITY, s = 0.f;
    float acc[4] = {0.f, 0.f, 0.f, 0.f};
    int p0 = offs[d], p1 = offs[d + 1];
    for (int p = p0; p < p1; ++p) {
        int srcn = csr[p];
        float xv[4];
        *(float4*)&xv[0] = *(const float4*)&xl[(size_t)srcn * 256 + q4];
        float e = 0.f;
        #pragma unroll
        for (int q = 0; q < 4; ++q) {
            float h = xv[q] + xrr[q];
            h = (h > 0.f) ? h : 0.2f * h;
            e += attr[q] * h;
        }
        #pragma unroll
        for (int msk = 1; msk < RW; msk <<= 1) e += __shfl_xor(e, msk);
        float mn = fmaxf(m, e);
        float sc = __expf(m - mn);
        float pe = __expf(e - mn);
        s = s * sc + pe;
        #pragma unroll
        for (int q = 0; q < 4; ++q) acc[q] = acc[q] * sc + pe * xv[q];
        m = mn;
    }
    float inv = 1.f / s;
    float* dp = &out[(size_t)d * ldo + q4];
    if (add_mode) {
        #pragma unroll
        for (int q = 0; q < 4; ++q) dp[q] += acc[q] * inv;
    } else {
        *(float4*)dp = make_float4(acc[0] * inv, acc[1] * inv, acc[2] * inv, acc[3] * inv);
    }
}

// ---------------------------------------------------------------------------
__global__ void elu_bias_kernel(float* __restrict__ h, const float* __restrict__ b0,
                                const float* __restrict__ b1, int total, int F) {
    int idx = blockIdx.x * blockDim.x + threadIdx.x;
    if (idx >= total) return;
    int c = idx % F;
    float v = h[idx] + b0[c] + b1[c];
    h[idx] = (v > 0.f) ? v : (__expf(v) - 1.f);
}

// ---------------------------------------------------------------------------
extern "C" void kernel_launch(void* const* d_in, const int* in_sizes, int n_in,
                              void* d_out, int out_size, void* d_ws, size_t ws_size,
                              hipStream_t stream) {
    const float* x      = (const float*)d_in[0];
    const int*   ei     = (const int*)d_in[1];
    const float* w1_l   = (const float*)d_in[2];
    const float* b1_l   = (const float*)d_in[3];
    const float* w1_r   = (const float*)d_in[4];
    const float* b1_r   = (const float*)d_in[5];
    const float* att1   = (const float*)d_in[6];
    const float* bias1  = (const float*)d_in[7];
    const float* w2_l   = (const float*)d_in[8];
    const float* b2_l   = (const float*)d_in[9];
    const float* w2_r   = (const float*)d_in[10];
    const float* b2_r   = (const float*)d_in[11];
    const float* att2   = (const float*)d_in[12];
    const float* bias2  = (const float*)d_in[13];
    const float* w_lin  = (const float*)d_in[14];
    const float* b_lin  = (const float*)d_in[15];
    float* out = (float*)d_out;

    // ---- workspace layout (~131 MB) ----
    float* h1   = (float*)d_ws;                        // [N][512]  61.44 MB
    float* bufA = h1 + (size_t)N_NODES * F1;           // [N][256]  30.72 MB
    float* bufB = bufA + (size_t)N_NODES * OUT_F;      // [N][256]  30.72 MB
    unsigned short* wt1h = (unsigned short*)(bufB + (size_t)N_NODES * OUT_F); // 8*64K
    unsigned short* wt1l = wt1h + 8 * 65536;
    unsigned short* wt2h = wt1l + 8 * 65536;           // 4*128K
    unsigned short* wt2l = wt2h + 4 * 131072;
    unsigned short* wtLh = wt2l + 4 * 131072;          // 64K
    unsigned short* wtLl = wtLh + 65536;
    int* count   = (int*)(wtLl + 65536);
    int* offsets = count + T_TYPES * N_NODES;
    int* csr     = offsets + T_TYPES * (N_NODES + 1);
    float* h2 = out;

    // --- weight pre-split (bf16 hi/lo, transposed to [n][k]) ---
    wconv1_kernel<<<(8 * 65536 + 255) / 256, 256, 0, stream>>>(w1_l, w1_r, wt1h, wt1l);
    wconv2_kernel<<<(4 * 131072 + 255) / 256, 256, 0, stream>>>(w2_l, w2_r, wt2h, wt2l);
    wlin_kernel<<<(65536 + 255) / 256, 256, 0, stream>>>(w_lin, wtLh, wtLl);

    // --- build CSR (by dst), shared by both convs ---
    zero_kernel<<<(T_TYPES * N_NODES + 255) / 256, 256, 0, stream>>>(count, T_TYPES * N_NODES);
    int eblocks = (T_TYPES * EP + 255) / 256;
    hist_kernel<<<eblocks, 256, 0, stream>>>(ei, count);
    scan_kernel<<<1, SCAN_T, 0, stream>>>(count, offsets);
    scatter_kernel<<<eblocks, 256, 0, stream>>>(ei, offsets, count, csr);

    int gat_blocks = N_NODES / 4;
    int gemm_grid = (N_NODES + 63) / 64;   // 469

    // --- conv1: per type t and head-half, xl/xr GEMMs then fused edge kernel ---
    for (int t = 0; t < T_TYPES; ++t) {
        for (int hh = 0; hh < 2; ++hh) {
            int co = hh * 256;
            int ml = (t * 2 + 0) * 2 + hh, mr = (t * 2 + 1) * 2 + hh;
            gemm_mfma_kernel<<<gemm_grid, 256, 0, stream>>>(
                x, D_IN, wt1h + (size_t)ml * 65536, wt1l + (size_t)ml * 65536,
                b1_l + t * F1 + co, bufA, N_NODES, D_IN);
            gemm_mfma_kernel<<<gemm_grid, 256, 0, stream>>>(
                x, D_IN, wt1h + (size_t)mr * 65536, wt1l + (size_t)mr * 65536,
                b1_r + t * F1 + co, bufB, N_NODES, D_IN);
            gat_edge_kernel<16><<<gat_blocks, 256, 0, stream>>>(
                bufA, bufB, att1 + t * F1 + co, offsets + t * (N_NODES + 1),
                csr + (size_t)t * EP, h1 + co, F1, t);
        }
    }
    elu_bias_kernel<<<(N_NODES * F1 + 255) / 256, 256, 0, stream>>>(
        h1, bias1, bias1 + F1, N_NODES * F1, F1);

    // --- conv2 (1 head, 256 cols) ---
    for (int t = 0; t < T_TYPES; ++t) {
        int ml = t * 2 + 0, mr = t * 2 + 1;
        gemm_mfma_kernel<<<gemm_grid, 256, 0, stream>>>(
            h1, F1, wt2h + (size_t)ml * 131072, wt2l + (size_t)ml * 131072,
            b2_l + t * OUT_F, bufA, N_NODES, F1);
        gemm_mfma_kernel<<<gemm_grid, 256, 0, stream>>>(
            h1, F1, wt2h + (size_t)mr * 131072, wt2l + (size_t)mr * 131072,
            b2_r + t * OUT_F, bufB, N_NODES, F1);
        gat_edge_kernel<64><<<gat_blocks, 256, 0, stream>>>(
            bufA, bufB, att2 + t * OUT_F, offsets + t * (N_NODES + 1),
            csr + (size_t)t * EP, h2, OUT_F, t);
    }
    elu_bias_kernel<<<(N_NODES * OUT_F + 255) / 256, 256, 0, stream>>>(
        h2, bias2, bias2 + OUT_F, N_NODES * OUT_F, OUT_F);

    // --- final linear: copy h2 (in d_out) to bufA, then GEMM back into d_out ---
    hipMemcpyAsync(bufA, h2, (size_t)N_NODES * OUT_F * sizeof(float),
                   hipMemcpyDeviceToDevice, stream);
    gemm_mfma_kernel<<<gemm_grid, 256, 0, stream>>>(
        bufA, OUT_F, wtLh, wtLl, b_lin, out, N_NODES, OUT_F);
}

// Round 5
// 905.472 us; speedup vs baseline: 1.8216x; 1.2043x over previous
//
#include <hip/hip_runtime.h>
#include <math.h>

#define N_NODES 30000
#define D_IN    256
#define E_EDGES 300000
#define T_TYPES 2
#define HEADS   8
#define HID     64
#define F1      512   // HEADS*HID
#define OUT_F   256
#define EP      (E_EDGES + N_NODES)   // 330000 edges per type incl self-loops

typedef __attribute__((ext_vector_type(8))) short bf16x8;
typedef __attribute__((ext_vector_type(4))) float f32x4;

__device__ __forceinline__ unsigned short f2bf(float f) {
    unsigned u = __float_as_uint(f);
    unsigned r = 0x7fffu + ((u >> 16) & 1u);
    return (unsigned short)((u + r) >> 16);
}
__device__ __forceinline__ float bf2f(unsigned short h) {
    return __uint_as_float(((unsigned)h) << 16);
}

// ---------------------------------------------------------------------------
// Fused prep: weight transpose+bf16 hi/lo split (conv1, conv2, lin) + zero the
// per-destination counters. One launch instead of four.
// ---------------------------------------------------------------------------
#define PREP_W1   (8 * 65536)
#define PREP_W2   (4 * 131072)
#define PREP_WL   65536
#define PREP_CNT  (T_TYPES * N_NODES)
#define PREP_TOT  (PREP_W1 + PREP_W2 + PREP_WL + PREP_CNT)

__global__ void prep_kernel(const float* __restrict__ w1_l, const float* __restrict__ w1_r,
                            const float* __restrict__ w2_l, const float* __restrict__ w2_r,
                            const float* __restrict__ w_lin,
                            unsigned short* __restrict__ wt1h, unsigned short* __restrict__ wt1l,
                            unsigned short* __restrict__ wt2h, unsigned short* __restrict__ wt2l,
                            unsigned short* __restrict__ wtLh, unsigned short* __restrict__ wtLl,
                            int* __restrict__ count) {
    int idx = blockIdx.x * blockDim.x + threadIdx.x;
    if (idx < PREP_W1) {
        int n = idx & 255, k = (idx >> 8) & 255, mat = idx >> 16;
        int h = mat & 1, lr = (mat >> 1) & 1, t = mat >> 2;
        const float* src = lr ? w1_r : w1_l;
        float v = src[(size_t)t * 256 * 512 + (size_t)k * 512 + h * 256 + n];
        unsigned short hi = f2bf(v);
        unsigned short lo = f2bf(v - bf2f(hi));
        size_t o = (size_t)mat * 65536 + (size_t)n * 256 + k;
        wt1h[o] = hi; wt1l[o] = lo;
        return;
    }
    idx -= PREP_W1;
    if (idx < PREP_W2) {
        int n = idx & 255, k = (idx >> 8) & 511, mat = idx >> 17;
        int lr = mat & 1, t = mat >> 1;
        const float* src = lr ? w2_r : w2_l;
        float v = src[(size_t)t * 512 * 256 + (size_t)k * 256 + n];
        unsigned short hi = f2bf(v);
        unsigned short lo = f2bf(v - bf2f(hi));
        size_t o = (size_t)mat * 131072 + (size_t)n * 512 + k;
        wt2h[o] = hi; wt2l[o] = lo;
        return;
    }
    idx -= PREP_W2;
    if (idx < PREP_WL) {
        int n = idx & 255, k = idx >> 8;
        float v = w_lin[k * 256 + n];
        unsigned short hi = f2bf(v);
        unsigned short lo = f2bf(v - bf2f(hi));
        size_t o = (size_t)n * 256 + k;
        wtLh[o] = hi; wtLl[o] = lo;
        return;
    }
    idx -= PREP_WL;
    if (idx < PREP_CNT) count[idx] = 0;
}

// ---------------------------------------------------------------------------
// CSR build: histogram -> parallel 3-stage scan -> scatter.
// ---------------------------------------------------------------------------
__global__ void hist_kernel(const int* __restrict__ ei, int* __restrict__ count) {
    int idx = blockIdx.x * blockDim.x + threadIdx.x;
    if (idx >= T_TYPES * EP) return;
    int t = idx / EP, i = idx - t * EP;
    int dst = (i < E_EDGES) ? ei[t * 2 * E_EDGES + E_EDGES + i] : (i - E_EDGES);
    atomicAdd(&count[t * N_NODES + dst], 1);
}

#define SCAN_NB 30   // blocks per type, 1024 elems each (30720 >= 30000)

// S1: per-block sums
__global__ __launch_bounds__(256) void scan_bsum_kernel(const int* __restrict__ cnt,
                                                        int* __restrict__ bsum) {
    int t = blockIdx.y, b = blockIdx.x;
    const int* c = cnt + t * N_NODES;
    int i0 = b * 1024 + threadIdx.x * 4;
    int s = 0;
    #pragma unroll
    for (int j = 0; j < 4; ++j) { int i = i0 + j; if (i < N_NODES) s += c[i]; }
    #pragma unroll
    for (int m = 1; m < 64; m <<= 1) s += __shfl_xor(s, m);
    __shared__ int wsum[4];
    int l = threadIdx.x & 63, w = threadIdx.x >> 6;
    if (l == 0) wsum[w] = s;
    __syncthreads();
    if (threadIdx.x == 0) bsum[t * SCAN_NB + b] = wsum[0] + wsum[1] + wsum[2] + wsum[3];
}

// S2: exclusive scan of the 30 block sums per type (tiny)
__global__ void scan_base_kernel(int* __restrict__ bsum) {
    int t = threadIdx.x;
    if (t >= T_TYPES) return;
    int acc = 0;
    for (int b = 0; b < SCAN_NB; ++b) {
        int v = bsum[t * SCAN_NB + b];
        bsum[t * SCAN_NB + b] = acc;
        acc += v;
    }
}

// S3: per-block exclusive scan + base -> offsets; zero counters (cursor reuse)
__global__ __launch_bounds__(256) void scan_write_kernel(int* __restrict__ cnt,
                                                         const int* __restrict__ bsum,
                                                         int* __restrict__ off) {
    int t = blockIdx.y, b = blockIdx.x;
    int tid = threadIdx.x;
    int* c = cnt + t * N_NODES;
    int* o = off + t * (N_NODES + 1);
    int i0 = b * 1024 + tid * 4;
    int v[4]; int s = 0;
    #pragma unroll
    for (int j = 0; j < 4; ++j) { int i = i0 + j; v[j] = (i < N_NODES) ? c[i] : 0; s += v[j]; }
    __shared__ int ps[256];
    ps[tid] = s;
    __syncthreads();
    for (int ofs = 1; ofs < 256; ofs <<= 1) {
        int x = (tid >= ofs) ? ps[tid - ofs] : 0;
        __syncthreads();
        ps[tid] += x;
        __syncthreads();
    }
    int base = bsum[t * SCAN_NB + b] + ps[tid] - s;
    #pragma unroll
    for (int j = 0; j < 4; ++j) {
        int i = i0 + j;
        if (i < N_NODES) { o[i] = base; base += v[j]; c[i] = 0; }
    }
    if (b == 0 && tid == 0) o[N_NODES] = EP;
}

__global__ void scatter_kernel(const int* __restrict__ ei, const int* __restrict__ offsets,
                               int* __restrict__ cursor, int* __restrict__ csr_src) {
    int idx = blockIdx.x * blockDim.x + threadIdx.x;
    if (idx >= T_TYPES * EP) return;
    int t = idx / EP, i = idx - t * EP;
    int src, dst;
    if (i < E_EDGES) {
        src = ei[t * 2 * E_EDGES + i];
        dst = ei[t * 2 * E_EDGES + E_EDGES + i];
    } else {
        src = dst = i - E_EDGES;
    }
    int pos = offsets[t * (N_NODES + 1) + dst] + atomicAdd(&cursor[t * N_NODES + dst], 1);
    csr_src[t * EP + pos] = src;
}

// ---------------------------------------------------------------------------
// Split-precision bf16x3 MFMA GEMM, dual-output: blockIdx.y in {0,1} selects
// (B, bias, C) set. C[M x 256] = A[M x K](fp32) @ W + bias.
// Tile BM=64 x BN=256 x BK=32, 4 waves, wave w owns cols [w*64,+64), 4x4
// 16x16x32 frags, XOR-swizzled A tile staged fp32->hi/lo.
// ---------------------------------------------------------------------------
__global__ __launch_bounds__(256) void gemm_mfma_kernel(
        const float* __restrict__ A, int lda,
        const unsigned short* __restrict__ Bh0, const unsigned short* __restrict__ Bl0,
        const float* __restrict__ bias0, float* __restrict__ C0,
        const unsigned short* __restrict__ Bh1, const unsigned short* __restrict__ Bl1,
        const float* __restrict__ bias1, float* __restrict__ C1,
        int M, int K) {
    const unsigned short* Bh = blockIdx.y ? Bh1 : Bh0;
    const unsigned short* Bl = blockIdx.y ? Bl1 : Bl0;
    const float* bias = blockIdx.y ? bias1 : bias0;
    float* C = blockIdx.y ? C1 : C0;

    __shared__ unsigned short Ah_s[64 * 32], Al_s[64 * 32];
    __shared__ unsigned short Bh_s[256 * 32], Bl_s[256 * 32];
    int t = threadIdx.x;
    int row0 = blockIdx.x * 64;
    int w = t >> 6;
    int l = t & 63;
    int fm = l & 15;
    int fg = l >> 4;

    f32x4 acc[4][4];
    const f32x4 zf = {0.f, 0.f, 0.f, 0.f};
    #pragma unroll
    for (int i = 0; i < 4; ++i)
        #pragma unroll
        for (int j = 0; j < 4; ++j) acc[i][j] = zf;

    int ar = t >> 3;
    int af = t & 7;
    int bn = t >> 2;
    int bb = t & 3;

    for (int k0 = 0; k0 < K; k0 += 32) {
        #pragma unroll
        for (int v = 0; v < 2; ++v) {
            int r = v * 32 + ar;
            int rg = row0 + r;
            float4 a4 = make_float4(0.f, 0.f, 0.f, 0.f);
            if (rg < M) a4 = *(const float4*)&A[(size_t)rg * lda + k0 + af * 4];
            ushort4 hi, lo;
            hi.x = f2bf(a4.x); lo.x = f2bf(a4.x - bf2f(hi.x));
            hi.y = f2bf(a4.y); lo.y = f2bf(a4.y - bf2f(hi.y));
            hi.z = f2bf(a4.z); lo.z = f2bf(a4.z - bf2f(hi.z));
            hi.w = f2bf(a4.w); lo.w = f2bf(a4.w - bf2f(hi.w));
            int ke = (af * 4) ^ (((r >> 1) & 3) << 3);
            *(ushort4*)&Ah_s[r * 32 + ke] = hi;
            *(ushort4*)&Al_s[r * 32 + ke] = lo;
        }
        #pragma unroll
        for (int g = 0; g < 4; ++g) {
            int n = g * 64 + bn;
            *(uint4*)&Bh_s[n * 32 + bb * 8] = *(const uint4*)&Bh[(size_t)n * K + k0 + bb * 8];
            *(uint4*)&Bl_s[n * 32 + bb * 8] = *(const uint4*)&Bl[(size_t)n * K + k0 + bb * 8];
        }
        __syncthreads();
        bf16x8 ah[4], al[4], bh[4], bl[4];
        #pragma unroll
        for (int i = 0; i < 4; ++i) {
            int r = i * 16 + fm;
            int ke = (fg * 8) ^ (((r >> 1) & 3) << 3);
            ah[i] = *(const bf16x8*)&Ah_s[r * 32 + ke];
            al[i] = *(const bf16x8*)&Al_s[r * 32 + ke];
        }
        #pragma unroll
        for (int j = 0; j < 4; ++j) {
            int n = w * 64 + j * 16 + fm;
            bh[j] = *(const bf16x8*)&Bh_s[n * 32 + fg * 8];
            bl[j] = *(const bf16x8*)&Bl_s[n * 32 + fg * 8];
        }
        #pragma unroll
        for (int i = 0; i < 4; ++i)
            #pragma unroll
            for (int j = 0; j < 4; ++j) {
                acc[i][j] = __builtin_amdgcn_mfma_f32_16x16x32_bf16(ah[i], bh[j], acc[i][j], 0, 0, 0);
                acc[i][j] = __builtin_amdgcn_mfma_f32_16x16x32_bf16(ah[i], bl[j], acc[i][j], 0, 0, 0);
                acc[i][j] = __builtin_amdgcn_mfma_f32_16x16x32_bf16(al[i], bh[j], acc[i][j], 0, 0, 0);
            }
        __syncthreads();
    }
    #pragma unroll
    for (int j = 0; j < 4; ++j) {
        int col = w * 64 + j * 16 + fm;
        float bv = bias[col];
        #pragma unroll
        for (int i = 0; i < 4; ++i) {
            #pragma unroll
            for (int q = 0; q < 4; ++q) {
                int rg = row0 + i * 16 + fg * 4 + q;
                if (rg < M) C[(size_t)rg * 256 + col] = acc[i][j][q] + bv;
            }
        }
    }
}

// ---------------------------------------------------------------------------
// Fused GATv2 edge kernel over a 256-column block. One wave per destination.
// MODE 0: out = result. MODE 2: out = elu(out + result + eb0[c] + eb1[c]).
// 2-edge unrolled gather loop for load-latency overlap.
// ---------------------------------------------------------------------------
template <int RW, int MODE>
__global__ __launch_bounds__(256) void gat_edge_kernel(
        const float* __restrict__ xl, const float* __restrict__ xr,
        const float* __restrict__ att,
        const int* __restrict__ offs, const int* __restrict__ csr,
        float* __restrict__ out, int ldo,
        const float* __restrict__ eb0, const float* __restrict__ eb1) {
    int wave = (blockIdx.x * blockDim.x + threadIdx.x) >> 6;
    int lane = threadIdx.x & 63;
    if (wave >= N_NODES) return;
    int d = wave;
    int q4 = lane * 4;
    float attr[4], xrr[4];
    *(float4*)&attr[0] = *(const float4*)&att[q4];
    *(float4*)&xrr[0]  = *(const float4*)&xr[(size_t)d * 256 + q4];
    float m = -INFINITY, s = 0.f;
    float acc[4] = {0.f, 0.f, 0.f, 0.f};
    int p0 = offs[d], p1 = offs[d + 1];
    int p = p0;
    for (; p + 2 <= p1; p += 2) {
        int s0 = csr[p], s1 = csr[p + 1];
        float xv0[4], xv1[4];
        *(float4*)&xv0[0] = *(const float4*)&xl[(size_t)s0 * 256 + q4];
        *(float4*)&xv1[0] = *(const float4*)&xl[(size_t)s1 * 256 + q4];
        float e0 = 0.f, e1 = 0.f;
        #pragma unroll
        for (int q = 0; q < 4; ++q) {
            float h0 = xv0[q] + xrr[q];
            float h1 = xv1[q] + xrr[q];
            h0 = (h0 > 0.f) ? h0 : 0.2f * h0;
            h1 = (h1 > 0.f) ? h1 : 0.2f * h1;
            e0 += attr[q] * h0;
            e1 += attr[q] * h1;
        }
        #pragma unroll
        for (int msk = 1; msk < RW; msk <<= 1) {
            e0 += __shfl_xor(e0, msk);
            e1 += __shfl_xor(e1, msk);
        }
        float mn = fmaxf(m, e0);
        float sc = __expf(m - mn);
        float pe = __expf(e0 - mn);
        s = s * sc + pe;
        #pragma unroll
        for (int q = 0; q < 4; ++q) acc[q] = acc[q] * sc + pe * xv0[q];
        m = mn;
        mn = fmaxf(m, e1);
        sc = __expf(m - mn);
        pe = __expf(e1 - mn);
        s = s * sc + pe;
        #pragma unroll
        for (int q = 0; q < 4; ++q) acc[q] = acc[q] * sc + pe * xv1[q];
        m = mn;
    }
    if (p < p1) {
        int s0 = csr[p];
        float xv0[4];
        *(float4*)&xv0[0] = *(const float4*)&xl[(size_t)s0 * 256 + q4];
        float e0 = 0.f;
        #pragma unroll
        for (int q = 0; q < 4; ++q) {
            float h0 = xv0[q] + xrr[q];
            h0 = (h0 > 0.f) ? h0 : 0.2f * h0;
            e0 += attr[q] * h0;
        }
        #pragma unroll
        for (int msk = 1; msk < RW; msk <<= 1) e0 += __shfl_xor(e0, msk);
        float mn = fmaxf(m, e0);
        float sc = __expf(m - mn);
        float pe = __expf(e0 - mn);
        s = s * sc + pe;
        #pragma unroll
        for (int q = 0; q < 4; ++q) acc[q] = acc[q] * sc + pe * xv0[q];
        m = mn;
    }
    float inv = 1.f / s;
    float* dp = &out[(size_t)d * ldo + q4];
    if (MODE == 0) {
        *(float4*)dp = make_float4(acc[0] * inv, acc[1] * inv, acc[2] * inv, acc[3] * inv);
    } else {
        #pragma unroll
        for (int q = 0; q < 4; ++q) {
            float v = dp[q] + acc[q] * inv + eb0[q4 + q] + eb1[q4 + q];
            dp[q] = (v > 0.f) ? v : (__expf(v) - 1.f);
        }
    }
}

// ---------------------------------------------------------------------------
extern "C" void kernel_launch(void* const* d_in, const int* in_sizes, int n_in,
                              void* d_out, int out_size, void* d_ws, size_t ws_size,
                              hipStream_t stream) {
    const float* x      = (const float*)d_in[0];
    const int*   ei     = (const int*)d_in[1];
    const float* w1_l   = (const float*)d_in[2];
    const float* b1_l   = (const float*)d_in[3];
    const float* w1_r   = (const float*)d_in[4];
    const float* b1_r   = (const float*)d_in[5];
    const float* att1   = (const float*)d_in[6];
    const float* bias1  = (const float*)d_in[7];
    const float* w2_l   = (const float*)d_in[8];
    const float* b2_l   = (const float*)d_in[9];
    const float* w2_r   = (const float*)d_in[10];
    const float* b2_r   = (const float*)d_in[11];
    const float* att2   = (const float*)d_in[12];
    const float* bias2  = (const float*)d_in[13];
    const float* w_lin  = (const float*)d_in[14];
    const float* b_lin  = (const float*)d_in[15];
    float* out = (float*)d_out;

    // ---- workspace layout (~131 MB) ----
    float* h1   = (float*)d_ws;                        // [N][512]  61.44 MB
    float* bufA = h1 + (size_t)N_NODES * F1;           // [N][256]  30.72 MB
    float* bufB = bufA + (size_t)N_NODES * OUT_F;      // [N][256]  30.72 MB
    unsigned short* wt1h = (unsigned short*)(bufB + (size_t)N_NODES * OUT_F);
    unsigned short* wt1l = wt1h + 8 * 65536;
    unsigned short* wt2h = wt1l + 8 * 65536;
    unsigned short* wt2l = wt2h + 4 * 131072;
    unsigned short* wtLh = wt2l + 4 * 131072;
    unsigned short* wtLl = wtLh + 65536;
    int* count   = (int*)(wtLl + 65536);
    int* offsets = count + T_TYPES * N_NODES;
    int* bsum    = offsets + T_TYPES * (N_NODES + 1);
    int* csr     = bsum + T_TYPES * SCAN_NB;
    float* h2 = out;

    // --- prep (weights split + count zero) ---
    prep_kernel<<<(PREP_TOT + 255) / 256, 256, 0, stream>>>(
        w1_l, w1_r, w2_l, w2_r, w_lin, wt1h, wt1l, wt2h, wt2l, wtLh, wtLl, count);

    // --- build CSR (by dst), shared by both convs ---
    int eblocks = (T_TYPES * EP + 255) / 256;
    hist_kernel<<<eblocks, 256, 0, stream>>>(ei, count);
    dim3 sgrid(SCAN_NB, T_TYPES);
    scan_bsum_kernel<<<sgrid, 256, 0, stream>>>(count, bsum);
    scan_base_kernel<<<1, 64, 0, stream>>>(bsum);
    scan_write_kernel<<<sgrid, 256, 0, stream>>>(count, bsum, offsets);
    scatter_kernel<<<eblocks, 256, 0, stream>>>(ei, offsets, count, csr);

    int gat_blocks = N_NODES / 4;
    dim3 ggrid((N_NODES + 63) / 64, 2);   // dual-output GEMM
    dim3 ggrid1((N_NODES + 63) / 64, 1);  // single-output GEMM

    // --- conv1: per (t, head-half): l+r GEMMs in one launch, then edge kernel ---
    for (int t = 0; t < T_TYPES; ++t) {
        for (int hh = 0; hh < 2; ++hh) {
            int co = hh * 256;
            int ml = (t * 2 + 0) * 2 + hh, mr = (t * 2 + 1) * 2 + hh;
            gemm_mfma_kernel<<<ggrid, 256, 0, stream>>>(
                x, D_IN,
                wt1h + (size_t)ml * 65536, wt1l + (size_t)ml * 65536, b1_l + t * F1 + co, bufA,
                wt1h + (size_t)mr * 65536, wt1l + (size_t)mr * 65536, b1_r + t * F1 + co, bufB,
                N_NODES, D_IN);
            if (t == 0)
                gat_edge_kernel<16, 0><<<gat_blocks, 256, 0, stream>>>(
                    bufA, bufB, att1 + t * F1 + co, offsets + t * (N_NODES + 1),
                    csr + (size_t)t * EP, h1 + co, F1, nullptr, nullptr);
            else
                gat_edge_kernel<16, 2><<<gat_blocks, 256, 0, stream>>>(
                    bufA, bufB, att1 + t * F1 + co, offsets + t * (N_NODES + 1),
                    csr + (size_t)t * EP, h1 + co, F1, bias1 + co, bias1 + F1 + co);
        }
    }

    // --- conv2 (1 head, 256 cols) ---
    for (int t = 0; t < T_TYPES; ++t) {
        int ml = t * 2 + 0, mr = t * 2 + 1;
        gemm_mfma_kernel<<<ggrid, 256, 0, stream>>>(
            h1, F1,
            wt2h + (size_t)ml * 131072, wt2l + (size_t)ml * 131072, b2_l + t * OUT_F, bufA,
            wt2h + (size_t)mr * 131072, wt2l + (size_t)mr * 131072, b2_r + t * OUT_F, bufB,
            N_NODES, F1);
        if (t == 0)
            gat_edge_kernel<64, 0><<<gat_blocks, 256, 0, stream>>>(
                bufA, bufB, att2 + t * OUT_F, offsets + t * (N_NODES + 1),
                csr + (size_t)t * EP, h2, OUT_F, nullptr, nullptr);
        else
            gat_edge_kernel<64, 2><<<gat_blocks, 256, 0, stream>>>(
                bufA, bufB, att2 + t * OUT_F, offsets + t * (N_NODES + 1),
                csr + (size_t)t * EP, h2, OUT_F, bias2, bias2 + OUT_F);
    }

    // --- final linear: copy h2 (in d_out) to bufA, then GEMM back into d_out ---
    hipMemcpyAsync(bufA, h2, (size_t)N_NODES * OUT_F * sizeof(float),
                   hipMemcpyDeviceToDevice, stream);
    gemm_mfma_kernel<<<ggrid1, 256, 0, stream>>>(
        bufA, OUT_F, wtLh, wtLl, b_lin, out, wtLh, wtLl, b_lin, out, N_NODES, OUT_F);
}